// Round 1
// baseline (3600.369 us; speedup 1.0000x reference)
//
#include <hip/hip_runtime.h>

namespace {
constexpr int Tn = 4096;
constexpr int Kn = 64;
constexpr int BATCH = 128;
constexpr int START_TAG = 62;
constexpr int STOP_TAG = 63;
constexpr float NEGV = -10000.0f;
constexpr int CH = 64;          // backtrace chunk length
constexpr int NCH = Tn / CH;    // 64 chunks

__global__ __launch_bounds__(64)
void crf_kernel(const float* __restrict__ feats,   // [B,T,K]
                const int* __restrict__ tags,      // [B,T]
                const float* __restrict__ trans,   // [K,K]  trans[next,prev]
                float* __restrict__ out,           // [B] nll | [B] path_score | [B,T] path
                unsigned char* __restrict__ bp_ws) // [B,T,K] backpointers
{
    const int lane = threadIdx.x;
    const int b = blockIdx.x & (BATCH - 1);
    const size_t fb = (size_t)b * Tn * Kn;

    __shared__ float sbuf[2][Kn];
    __shared__ unsigned char snap[NCH * Kn];
    __shared__ unsigned char echain[NCH];

    if (blockIdx.x < BATCH) {
        // ================= forward partition + gold score -> nll =================
        // ---- gold path score: lane covers a contiguous 64-step chunk ----
        float gold = 0.0f;
        {
            const int t0 = lane * (Tn / 64);
            int prev = (lane == 0) ? START_TAG : tags[(size_t)b * Tn + t0 - 1];
            for (int k = 0; k < Tn / 64; ++k) {
                const int t = t0 + k;
                const int tg = tags[(size_t)b * Tn + t];
                gold += trans[tg * Kn + prev] + feats[fb + (size_t)t * Kn + tg];
                prev = tg;
            }
            if (lane == 63) gold += trans[STOP_TAG * Kn + prev];  // trans[STOP, tags[-1]]
        }
        #pragma unroll
        for (int off = 32; off; off >>= 1) gold += __shfl_down(gold, off);
        // gold total now on lane 0

        // ---- E row (exp of transitions) into registers: lane j owns trans[j,:] ----
        float E[Kn];
        #pragma unroll
        for (int q = 0; q < Kn / 4; ++q) {
            const float4 t4 = ((const float4*)(trans + lane * Kn))[q];
            E[4*q+0] = __expf(t4.x);
            E[4*q+1] = __expf(t4.y);
            E[4*q+2] = __expf(t4.z);
            E[4*q+3] = __expf(t4.w);
        }

        // ---- step 0 exact (one-hot init at START) ----
        float a = trans[lane * Kn + START_TAG] + feats[fb + lane];

        for (int t = 1; t < Tn; ++t) {
            const float f = feats[fb + (size_t)t * Kn + lane];   // prefetch emission
            const float m = __shfl(a, 0);                        // normalizer (lane0 alpha)
            float* vb = sbuf[t & 1];
            vb[lane] = __expf(a - m);
            __syncthreads();
            float s0 = 0.f, s1 = 0.f, s2 = 0.f, s3 = 0.f;
            #pragma unroll
            for (int q = 0; q < Kn / 4; ++q) {
                const float4 vv = ((const float4*)vb)[q];
                s0 = fmaf(E[4*q+0], vv.x, s0);
                s1 = fmaf(E[4*q+1], vv.y, s1);
                s2 = fmaf(E[4*q+2], vv.z, s2);
                s3 = fmaf(E[4*q+3], vv.w, s3);
            }
            a = m + __logf((s0 + s1) + (s2 + s3)) + f;
        }

        // ---- forward_score = logsumexp(alpha + trans[STOP,:]) ----
        const float x = a + trans[STOP_TAG * Kn + lane];  // may be -inf on START lane: ok
        float mx = x;
        #pragma unroll
        for (int off = 32; off; off >>= 1) mx = fmaxf(mx, __shfl_xor(mx, off));
        float se = __expf(x - mx);
        #pragma unroll
        for (int off = 32; off; off >>= 1) se += __shfl_xor(se, off);
        if (lane == 0) out[b] = (mx + __logf(se)) - gold;
    } else {
        // ================= Viterbi decode =================
        float tr[Kn];
        #pragma unroll
        for (int q = 0; q < Kn / 4; ++q) {
            const float4 t4 = ((const float4*)(trans + lane * Kn))[q];
            tr[4*q+0] = t4.x; tr[4*q+1] = t4.y; tr[4*q+2] = t4.z; tr[4*q+3] = t4.w;
        }
        float d = (lane == START_TAG) ? 0.0f : NEGV;
        int h = lane;  // running composed backpointer table: h[x] = tag before chunk, given tag x now
        for (int t = 0; t < Tn; ++t) {
            const float f = feats[fb + (size_t)t * Kn + lane];
            float* db = sbuf[t & 1];
            db[lane] = d;
            __syncthreads();
            float best = -__builtin_inff();
            int bp = 0;
            #pragma unroll
            for (int q = 0; q < Kn / 4; ++q) {
                const float4 dv = ((const float4*)db)[q];
                { const float s = dv.x + tr[4*q+0]; if (s > best) { best = s; bp = 4*q+0; } }
                { const float s = dv.y + tr[4*q+1]; if (s > best) { best = s; bp = 4*q+1; } }
                { const float s = dv.z + tr[4*q+2]; if (s > best) { best = s; bp = 4*q+2; } }
                { const float s = dv.w + tr[4*q+3]; if (s > best) { best = s; bp = 4*q+3; } }
            }
            d = best + f;  // feat added after argmax, as in reference
            bp_ws[((size_t)b * Tn + t) * Kn + lane] = (unsigned char)bp;
            h = __shfl(h, bp);  // compose backpointer function
            if ((t & (CH - 1)) == (CH - 1)) {
                snap[(t / CH) * Kn + lane] = (unsigned char)h;  // chunk-composed table
                h = lane;
            }
        }
        // ---- terminal argmax (first index on ties, as jnp.argmax) ----
        const float term = d + trans[STOP_TAG * Kn + lane];
        float bv = term;
        int bi = lane;
        #pragma unroll
        for (int off = 32; off; off >>= 1) {
            const float ov = __shfl_xor(bv, off);
            const int oi = __shfl_xor(bi, off);
            if (ov > bv || (ov == bv && oi < bi)) { bv = ov; bi = oi; }
        }
        if (lane == 0) out[BATCH + b] = bv;   // path_score
        __syncthreads();
        // ---- chunk-boundary tags via composed tables (64 dependent LDS reads) ----
        if (lane == 0) {
            int e = bi;  // tag at end of chunk NCH-1 (= t = Tn-1)
            for (int c = NCH - 1; c >= 0; --c) {
                echain[c] = (unsigned char)e;      // tag at t = 64c+63
                e = snap[c * Kn + e];              // tag at t = 64c-1 = end of chunk c-1
            }
        }
        __syncthreads();
        // ---- within-chunk reconstruction: lane = chunk, 64 dependent loads each ----
        {
            int tag = echain[lane];
            float* po = out + 2 * BATCH + (size_t)b * Tn;
            for (int k = CH - 1; k >= 0; --k) {
                const int t = lane * CH + k;
                po[t] = (float)tag;
                tag = bp_ws[((size_t)b * Tn + t) * Kn + tag];
            }
        }
    }
}
} // namespace

extern "C" void kernel_launch(void* const* d_in, const int* in_sizes, int n_in,
                              void* d_out, int out_size, void* d_ws, size_t ws_size,
                              hipStream_t stream)
{
    const float* feats = (const float*)d_in[0];
    const int* tags   = (const int*)d_in[1];
    const float* trans = (const float*)d_in[2];
    float* out = (float*)d_out;
    unsigned char* bp = (unsigned char*)d_ws;  // needs 128*4096*64 = 32 MB
    hipLaunchKernelGGL(crf_kernel, dim3(2 * BATCH), dim3(64), 0, stream,
                       feats, tags, trans, out, bp);
}

// Round 2
// 2616.843 us; speedup vs baseline: 1.3758x; 1.3758x over previous
//
#include <hip/hip_runtime.h>

namespace {
constexpr int Tn = 4096;
constexpr int Kn = 64;
constexpr int BATCH = 128;
constexpr int START_TAG = 62;
constexpr int STOP_TAG = 63;
constexpr float NEGV = -10000.0f;
constexpr int CH = 64;          // backtrace chunk length
constexpr int NCH = Tn / CH;    // 64 chunks

__device__ __forceinline__ float rfl(float x) {
    return __uint_as_float(__builtin_amdgcn_readfirstlane(__float_as_uint(x)));
}

__global__ __launch_bounds__(64)
void crf_kernel(const float* __restrict__ feats,   // [B,T,K]
                const int* __restrict__ tags,      // [B,T]
                const float* __restrict__ trans,   // [K,K]  trans[next,prev]
                float* __restrict__ out,           // [B] nll | [B] path_score | [B,T] path
                unsigned char* __restrict__ bp_ws) // [B,T,K] backpointers
{
    const int lane = threadIdx.x;
    const int b = blockIdx.x & (BATCH - 1);
    const size_t fb = (size_t)b * Tn * Kn;

    __shared__ float sbuf[2][Kn];
    __shared__ unsigned char snap[NCH * Kn];
    __shared__ unsigned char echain[NCH];

    if (blockIdx.x < BATCH) {
        // ================= forward partition + gold score -> nll =================
        float gold = 0.0f;
        {
            const int t0 = lane * (Tn / 64);
            int prev = (lane == 0) ? START_TAG : tags[(size_t)b * Tn + t0 - 1];
            for (int k = 0; k < Tn / 64; ++k) {
                const int t = t0 + k;
                const int tg = tags[(size_t)b * Tn + t];
                gold += trans[tg * Kn + prev] + feats[fb + (size_t)t * Kn + tg];
                prev = tg;
            }
            if (lane == 63) gold += trans[STOP_TAG * Kn + prev];  // trans[STOP, tags[-1]]
        }
        #pragma unroll
        for (int off = 32; off; off >>= 1) gold += __shfl_down(gold, off);
        // gold total now on lane 0

        // ---- E row (exp of transitions): lane j owns trans[j,:] ----
        float E[Kn];
        #pragma unroll
        for (int q = 0; q < Kn / 4; ++q) {
            const float4 t4 = ((const float4*)(trans + lane * Kn))[q];
            E[4*q+0] = __expf(t4.x);
            E[4*q+1] = __expf(t4.y);
            E[4*q+2] = __expf(t4.z);
            E[4*q+3] = __expf(t4.w);
        }

        // ---- step 0 exact (one-hot init at START) ----
        float a = trans[lane * Kn + START_TAG] + feats[fb + lane];

        auto fwd_step = [&](float f, int t) {
            const float m = rfl(a);                      // cheap wave-uniform normalizer
            float* vb = sbuf[t & 1];
            vb[lane] = __expf(a - m);
            __syncthreads();
            float s0 = 0.f, s1 = 0.f, s2 = 0.f, s3 = 0.f;
            #pragma unroll
            for (int q = 0; q < Kn / 4; ++q) {
                const float4 vv = ((const float4*)vb)[q];
                s0 = fmaf(E[4*q+0], vv.x, s0);
                s1 = fmaf(E[4*q+1], vv.y, s1);
                s2 = fmaf(E[4*q+2], vv.z, s2);
                s3 = fmaf(E[4*q+3], vv.w, s3);
            }
            a = m + __logf((s0 + s1) + (s2 + s3)) + f;
        };

        // ---- main loop with 4-deep feats prefetch ----
        float fp[4];
        #pragma unroll
        for (int k = 0; k < 4; ++k)
            fp[k] = feats[fb + (size_t)(1 + k) * Kn + lane];
        int t = 1;
        for (; t + 3 < Tn; t += 4) {
            float fn[4];
            #pragma unroll
            for (int k = 0; k < 4; ++k) {
                int tt = t + 4 + k; tt = tt < Tn ? tt : (Tn - 1);
                fn[k] = feats[fb + (size_t)tt * Kn + lane];
            }
            #pragma unroll
            for (int k = 0; k < 4; ++k) fwd_step(fp[k], t + k);
            #pragma unroll
            for (int k = 0; k < 4; ++k) fp[k] = fn[k];
        }
        for (; t < Tn; ++t) fwd_step(feats[fb + (size_t)t * Kn + lane], t);

        // ---- forward_score = logsumexp(alpha + trans[STOP,:]) ----
        const float x = a + trans[STOP_TAG * Kn + lane];
        float mx = x;
        #pragma unroll
        for (int off = 32; off; off >>= 1) mx = fmaxf(mx, __shfl_xor(mx, off));
        float se = __expf(x - mx);
        #pragma unroll
        for (int off = 32; off; off >>= 1) se += __shfl_xor(se, off);
        if (lane == 0) out[b] = (mx + __logf(se)) - gold;
    } else {
        // ================= Viterbi decode =================
        float tr[Kn];
        #pragma unroll
        for (int q = 0; q < Kn / 4; ++q) {
            const float4 t4 = ((const float4*)(trans + lane * Kn))[q];
            tr[4*q+0] = t4.x; tr[4*q+1] = t4.y; tr[4*q+2] = t4.z; tr[4*q+3] = t4.w;
        }
        float d = (lane == START_TAG) ? 0.0f : NEGV;
        int h = lane;  // running composed backpointer table

        auto vit_step = [&](float f, int t) {
            float* db = sbuf[t & 1];
            db[lane] = d;
            __syncthreads();
            // tree argmax: 16 independent groups of 4, then 16->1 binary tree.
            // strict '>' everywhere + (lower index on left) == first-max tie semantics
            float gv[16]; int gi[16];
            #pragma unroll
            for (int q = 0; q < 16; ++q) {
                const float4 dv = ((const float4*)db)[q];
                const float sx = dv.x + tr[4*q+0];
                const float sy = dv.y + tr[4*q+1];
                const float sz = dv.z + tr[4*q+2];
                const float sw = dv.w + tr[4*q+3];
                const bool c01 = sy > sx;
                const float v01 = c01 ? sy : sx; const int i01 = c01 ? (4*q+1) : (4*q+0);
                const bool c23 = sw > sz;
                const float v23 = c23 ? sw : sz; const int i23 = c23 ? (4*q+3) : (4*q+2);
                const bool cq = v23 > v01;
                gv[q] = cq ? v23 : v01; gi[q] = cq ? i23 : i01;
            }
            #pragma unroll
            for (int off = 8; off; off >>= 1) {
                #pragma unroll
                for (int q = 0; q < off; ++q) {
                    const bool c = gv[q + off] > gv[q];
                    gv[q] = c ? gv[q + off] : gv[q];
                    gi[q] = c ? gi[q + off] : gi[q];
                }
            }
            const int bp = gi[0];
            d = gv[0] + f;  // feat added after argmax, as in reference
            bp_ws[((size_t)b * Tn + t) * Kn + lane] = (unsigned char)bp;
            h = __shfl(h, bp);  // compose backpointer function (off critical path)
            if ((t & (CH - 1)) == (CH - 1)) {
                snap[(t / CH) * Kn + lane] = (unsigned char)h;
                h = lane;
            }
        };

        // ---- main loop with 4-deep feats prefetch (Tn % 4 == 0: no peel) ----
        float fp[4];
        #pragma unroll
        for (int k = 0; k < 4; ++k)
            fp[k] = feats[fb + (size_t)k * Kn + lane];
        for (int t = 0; t < Tn; t += 4) {
            float fn[4];
            #pragma unroll
            for (int k = 0; k < 4; ++k) {
                int tt = t + 4 + k; tt = tt < Tn ? tt : (Tn - 1);
                fn[k] = feats[fb + (size_t)tt * Kn + lane];
            }
            #pragma unroll
            for (int k = 0; k < 4; ++k) vit_step(fp[k], t + k);
            #pragma unroll
            for (int k = 0; k < 4; ++k) fp[k] = fn[k];
        }

        // ---- terminal argmax (first index on ties) ----
        const float term = d + trans[STOP_TAG * Kn + lane];
        float bv = term;
        int bi = lane;
        #pragma unroll
        for (int off = 32; off; off >>= 1) {
            const float ov = __shfl_xor(bv, off);
            const int oi = __shfl_xor(bi, off);
            if (ov > bv || (ov == bv && oi < bi)) { bv = ov; bi = oi; }
        }
        if (lane == 0) out[BATCH + b] = bv;   // path_score
        __syncthreads();
        // ---- chunk-boundary tags via composed tables ----
        if (lane == 0) {
            int e = bi;
            for (int c = NCH - 1; c >= 0; --c) {
                echain[c] = (unsigned char)e;
                e = snap[c * Kn + e];
            }
        }
        __syncthreads();
        // ---- within-chunk reconstruction: lane = chunk ----
        {
            int tag = echain[lane];
            float* po = out + 2 * BATCH + (size_t)b * Tn;
            for (int k = CH - 1; k >= 0; --k) {
                const int t = lane * CH + k;
                po[t] = (float)tag;
                tag = bp_ws[((size_t)b * Tn + t) * Kn + tag];
            }
        }
    }
}
} // namespace

extern "C" void kernel_launch(void* const* d_in, const int* in_sizes, int n_in,
                              void* d_out, int out_size, void* d_ws, size_t ws_size,
                              hipStream_t stream)
{
    const float* feats = (const float*)d_in[0];
    const int* tags   = (const int*)d_in[1];
    const float* trans = (const float*)d_in[2];
    float* out = (float*)d_out;
    unsigned char* bp = (unsigned char*)d_ws;  // needs 128*4096*64 = 32 MB
    hipLaunchKernelGGL(crf_kernel, dim3(2 * BATCH), dim3(64), 0, stream,
                       feats, tags, trans, out, bp);
}